// Round 2
// baseline (5250.333 us; speedup 1.0000x reference)
//
#include <hip/hip_runtime.h>

typedef __bf16 bf16;
typedef __bf16 bf16x8 __attribute__((ext_vector_type(8)));
typedef float  f32x4  __attribute__((ext_vector_type(4)));
typedef unsigned int       u32;
typedef unsigned short     u16;
typedef unsigned long long u64;

__device__ __forceinline__ f32x4 mfma16(bf16x8 a, bf16x8 b, f32x4 c) {
  return __builtin_amdgcn_mfma_f32_16x16x32_bf16(a, b, c, 0, 0, 0);
}
__device__ __forceinline__ float sigm(float x)  { return 1.0f / (1.0f + __expf(-x)); }
__device__ __forceinline__ float tanh_(float x) { return 2.0f / (1.0f + __expf(-2.0f * x)) - 1.0f; }
__device__ __forceinline__ float softplus_(float x) {
  return fmaxf(x, 0.0f) + __logf(1.0f + __expf(-fabsf(x)));
}
__device__ __forceinline__ float leaky_(float x) { return x > 0.0f ? x : 0.01f * x; }
__device__ __forceinline__ u16 bfbits(float f) { return __builtin_bit_cast(u16, (bf16)f); }

// ---------------- prep kernels (fp32 in -> bf16 out) ----------------

__global__ void k_transpose(const float* __restrict__ src, bf16* __restrict__ dst, int K, int N) {
  int i = blockIdx.x * 256 + threadIdx.x;
  if (i < K * N) { int k = i / N; int n = i - k * N; dst[n * K + k] = (bf16)src[i]; }
}

__global__ void k_p2(const float* __restrict__ pred, const float* __restrict__ dp, bf16* __restrict__ P2T) {
  int i = blockIdx.x * 256 + threadIdx.x;   // 65536
  int irow = i >> 8, n = i & 255;
  float acc = 0.0f;
  for (int j = 0; j < 256; ++j) {
    float p = pred[irow * 256 + j] - (j == irow ? 1.0f : 0.0f);
    acc += p * dp[j * 256 + n];
  }
  P2T[n * 256 + irow] = (bf16)acc;
}

__global__ void k_p1(const float* __restrict__ pred, const float* __restrict__ g1, bf16* __restrict__ P1T) {
  int i = blockIdx.x * 256 + threadIdx.x;   // 8192
  int irow = i >> 5, n = i & 31;
  float acc = 0.0f;
  for (int j = 0; j < 256; ++j) {
    float p = pred[irow * 256 + j] - (j == irow ? 1.0f : 0.0f);
    acc += p * g1[j * 32 + n];
  }
  P1T[n * 256 + irow] = (bf16)acc;
}

__global__ void k_cvec(const float* __restrict__ pred_b, const float* __restrict__ dp,
                       const float* __restrict__ g1, const float* __restrict__ g1_b,
                       float* __restrict__ c2f, float* __restrict__ c1f) {
  int n = threadIdx.x;  // 256 threads
  float acc = 0.0f;
  for (int j = 0; j < 256; ++j) acc += pred_b[j] * dp[j * 256 + n];
  c2f[n] = acc;
  if (n < 32) {
    float a2 = 0.0f;
    for (int j = 0; j < 256; ++j) a2 += pred_b[j] * g1[j * 32 + n];
    c1f[n] = a2 + g1_b[n];
  }
}

__global__ void k_zero(u32* __restrict__ p, int n) {
  int i = blockIdx.x * 256 + threadIdx.x;
  if (i < n) p[i] = 0;
}

// ---------------- phase 1: x = leaky(leaky(LN(obs@obs_W+b))@enc_W+b)@pre_W+b) ----------------

__global__ __launch_bounds__(256, 2) void k_phase1(
    const float* __restrict__ obs,
    const bf16* __restrict__ obs_WT, const bf16* __restrict__ enc_WT, const bf16* __restrict__ pre_WT,
    const float* __restrict__ obs_b, const float* __restrict__ enc_b, const float* __restrict__ pre_b,
    float* __restrict__ out)
{
  const int tid  = threadIdx.x;
  const int lane = tid & 63;
  const int w    = tid >> 6;       // wave 0..3
  const int n16  = lane & 15, quad = lane >> 4;
  const long R0  = (long)blockIdx.x * 64;

  __shared__ __align__(16) bf16 obsb[64][72];
  __shared__ __align__(16) bf16 ebuf[64][264];
  __shared__ __align__(16) bf16 e2buf[64][264];
  __shared__ float red[64][8];

  { // load obs tile 64x64 (fp32 -> bf16)
    int row = tid >> 2, col = (tid & 3) * 16;
    const float* src = obs + (R0 + row) * 64 + col;
    #pragma unroll
    for (int q = 0; q < 16; ++q) obsb[row][col + q] = (bf16)src[q];
  }
  __syncthreads();

  // G1: e0 = obs @ obs_W + obs_b  (K=64)
  {
    f32x4 acc[4][4] = {};
    #pragma unroll
    for (int ks = 0; ks < 2; ++ks) {
      bf16x8 a[4];
      #pragma unroll
      for (int mt = 0; mt < 4; ++mt) a[mt] = *(const bf16x8*)&obsb[mt * 16 + n16][ks * 32 + quad * 8];
      #pragma unroll
      for (int nt = 0; nt < 4; ++nt) {
        int ncol = (4 * w + nt) * 16 + n16;
        bf16x8 b = *(const bf16x8*)(obs_WT + ncol * 64 + ks * 32 + quad * 8);
        #pragma unroll
        for (int mt = 0; mt < 4; ++mt) acc[mt][nt] = mfma16(a[mt], b, acc[mt][nt]);
      }
    }
    #pragma unroll
    for (int nt = 0; nt < 4; ++nt) {
      int ncol = (4 * w + nt) * 16 + n16;
      float bb = obs_b[ncol];
      #pragma unroll
      for (int mt = 0; mt < 4; ++mt)
        #pragma unroll
        for (int reg = 0; reg < 4; ++reg)
          ebuf[mt * 16 + quad * 4 + reg][ncol] = (bf16)(acc[mt][nt][reg] + bb);
    }
  }
  __syncthreads();
  // LayerNorm over 256 (no affine)
  {
    int row = tid >> 2, qt = tid & 3;
    float s = 0, s2 = 0;
    for (int c = 0; c < 64; ++c) { float v = (float)ebuf[row][qt * 64 + c]; s += v; s2 += v * v; }
    red[row][qt] = s; red[row][4 + qt] = s2;
  }
  __syncthreads();
  if (tid < 64) {
    float s  = red[tid][0] + red[tid][1] + red[tid][2] + red[tid][3];
    float s2 = red[tid][4] + red[tid][5] + red[tid][6] + red[tid][7];
    float mu = s * (1.0f / 256.0f);
    float var = s2 * (1.0f / 256.0f) - mu * mu;
    red[tid][0] = mu; red[tid][1] = rsqrtf(var + 1e-5f);
  }
  __syncthreads();
  {
    int row = tid >> 2, qt = tid & 3;
    float mu = red[row][0], rstd = red[row][1];
    for (int c = 0; c < 64; ++c) {
      int cc = qt * 64 + c;
      ebuf[row][cc] = (bf16)(((float)ebuf[row][cc] - mu) * rstd);
    }
  }
  __syncthreads();
  // G2: e1 = leaky(e0n @ enc_W + enc_b)
  {
    f32x4 acc[4][4] = {};
    #pragma unroll
    for (int ks = 0; ks < 8; ++ks) {
      bf16x8 a[4];
      #pragma unroll
      for (int mt = 0; mt < 4; ++mt) a[mt] = *(const bf16x8*)&ebuf[mt * 16 + n16][ks * 32 + quad * 8];
      #pragma unroll
      for (int nt = 0; nt < 4; ++nt) {
        int ncol = (4 * w + nt) * 16 + n16;
        bf16x8 b = *(const bf16x8*)(enc_WT + ncol * 256 + ks * 32 + quad * 8);
        #pragma unroll
        for (int mt = 0; mt < 4; ++mt) acc[mt][nt] = mfma16(a[mt], b, acc[mt][nt]);
      }
    }
    #pragma unroll
    for (int nt = 0; nt < 4; ++nt) {
      int ncol = (4 * w + nt) * 16 + n16;
      float bb = enc_b[ncol];
      #pragma unroll
      for (int mt = 0; mt < 4; ++mt)
        #pragma unroll
        for (int reg = 0; reg < 4; ++reg)
          e2buf[mt * 16 + quad * 4 + reg][ncol] = (bf16)leaky_(acc[mt][nt][reg] + bb);
    }
  }
  __syncthreads();
  // G3: x = leaky(e1 @ pre_W + pre_b) -> global fp32 (d_out doubles as x buffer)
  {
    f32x4 acc[4][4] = {};
    #pragma unroll
    for (int ks = 0; ks < 8; ++ks) {
      bf16x8 a[4];
      #pragma unroll
      for (int mt = 0; mt < 4; ++mt) a[mt] = *(const bf16x8*)&e2buf[mt * 16 + n16][ks * 32 + quad * 8];
      #pragma unroll
      for (int nt = 0; nt < 4; ++nt) {
        int ncol = (4 * w + nt) * 16 + n16;
        bf16x8 b = *(const bf16x8*)(pre_WT + ncol * 256 + ks * 32 + quad * 8);
        #pragma unroll
        for (int mt = 0; mt < 4; ++mt) acc[mt][nt] = mfma16(a[mt], b, acc[mt][nt]);
      }
    }
    #pragma unroll
    for (int nt = 0; nt < 4; ++nt) {
      int ncol = (4 * w + nt) * 16 + n16;
      float bb = pre_b[ncol];
      #pragma unroll
      for (int mt = 0; mt < 4; ++mt)
        #pragma unroll
        for (int reg = 0; reg < 4; ++reg)
          out[(R0 + mt * 16 + quad * 4 + reg) * 256 + ncol] = leaky_(acc[mt][nt][reg] + bb);
    }
  }
}

// ---------------- phase 2: column-split persistent recurrent scan (Q=8) ----------------
// 512 wgs x 128 thr (2 waves). Group g = bid>>3 owns batch rows 16g..16g+15;
// eighth q = bid&7 owns h-cols [32q,32q+32). Wave w owns col c = 32q+16w+n16.
// Two independent chains per CU (different groups) overlap each other's
// MALL-exchange and L2-stream stalls; per-wg weight traffic halves vs Q=4.
// Exchange protocol unchanged: rh (bf16 u64-packed) via rhx, h_new rides `out`,
// per-group monotonic flags (8 publishers per group per step).

__global__ __launch_bounds__(128, 2) void k_phase2(
    const float* __restrict__ h0,
    const int*  __restrict__ epoch_p,
    float* __restrict__ out,
    const bf16* __restrict__ WrzT, const bf16* __restrict__ WnT,
    const bf16* __restrict__ P2T,  const bf16* __restrict__ P1T,
    const bf16* __restrict__ g2T,  const bf16* __restrict__ g3T,
    const float* __restrict__ c2f, const float* __restrict__ c1f,
    const float* __restrict__ Wrz_b, const float* __restrict__ Wn_b,
    const float* __restrict__ g2_b,  const float* __restrict__ g3_b,
    const float* __restrict__ ln_g,  const float* __restrict__ ln_b,
    u64* __restrict__ rhx, u32* __restrict__ rhflag, u32* __restrict__ hflag)
{
  const int tid  = threadIdx.x;
  const int lane = tid & 63;
  const int w    = tid >> 6;        // wave 0..1
  const int n16  = lane & 15;
  const int quad = lane >> 4;
  const int g    = blockIdx.x >> 3; // batch group 0..63
  const int q    = blockIdx.x & 7;  // column eighth 0..7
  const int b0   = g * 16;
  const int c    = q * 32 + w * 16 + n16;   // own global h-col

  __shared__ __align__(16) bf16  Abuf[16][520];   // [x_t | h-then-rh]
  __shared__ __align__(16) float gbuf[16][36];
  __shared__ __align__(16) bf16  gact[16][40];
  __shared__ __align__(16) bf16  g2act[16][40];
  __shared__ float lngs[32], lnbs[32];

  if (tid < 32) { lngs[tid] = ln_g[tid]; lnbs[tid] = ln_b[tid]; }

  const int ep = *epoch_p;
  const float scale = fminf(1.0f, fmaxf(0.0f, ((float)ep - 5.0f) / 40.0f));

  const float brz_r = Wrz_b[c];
  const float brz_z = Wrz_b[256 + c];
  const float bwn   = Wn_b[c];
  const float bg3e  = g3_b[c];
  const float bg3t  = g3_b[256 + c];
  const float bg3a  = g3_b[512 + c];
  const float c2v   = c2f[c];
  const float c1v   = c1f[w * 16 + n16];
  const float g2bv0 = g2_b[n16];
  const float g2bv1 = g2_b[16 + n16];

  // own-column fp32 h state: rows quad*4+r, col c
  float hreg[4];
  #pragma unroll
  for (int r = 0; r < 4; ++r)
    hreg[r] = h0[(long)(b0 + quad * 4 + r) * 256 + c];

  const int srow = tid >> 3;          // 0..15
  const int scol = (tid & 7) * 32;    // 0..224

  { // stage x_0 and full h0 (bf16) into Abuf (32 cols per thread)
    const float* hp = h0 + (long)(b0 + srow) * 256 + scol;
    const float* xp = out + ((long)(b0 + srow) * 256 + 0) * 256 + scol;
    #pragma unroll
    for (int k = 0; k < 4; ++k) {
      bf16x8 xv, hv;
      #pragma unroll
      for (int j = 0; j < 8; ++j) { xv[j] = (bf16)xp[k * 8 + j]; hv[j] = (bf16)hp[k * 8 + j]; }
      *(bf16x8*)&Abuf[srow][scol + k * 8]       = xv;
      *(bf16x8*)&Abuf[srow][256 + scol + k * 8] = hv;
    }
  }
  __syncthreads();

  const bf16* Ab = &Abuf[n16][quad * 8];
  u32* rhF = rhflag + g * 16;   // 64B-strided per-group flags
  u32* hF  = hflag  + g * 16;

  for (int t = 0; t < 256; ++t) {
    const bool notlast = (t < 255);

    // prefetch x_{t+1} early (consumed after bar5; latency hidden under the step)
    f32x4 xr[8];
    #pragma unroll
    for (int j = 0; j < 8; ++j) xr[j] = f32x4{0, 0, 0, 0};
    if (notlast) {
      const float* xp = out + ((long)(b0 + srow) * 256 + (t + 1)) * 256 + scol;
      #pragma unroll
      for (int j = 0; j < 8; ++j) xr[j] = *(const f32x4*)(xp + 4 * j);
    }

    // ---- S2: rz (K=512 [x|h]), dh = h@P2 (K=256), g1 = h@P1 ----
    f32x4 accr = {}, accz = {}, accdh = {}, accg = {}, accn = {};
    #pragma unroll
    for (int ks = 0; ks < 16; ++ks) {
      bf16x8 a = *(const bf16x8*)(Ab + ks * 32);
      const bf16* bp = WrzT + (long)c * 512 + ks * 32 + quad * 8;
      accr = mfma16(a, *(const bf16x8*)(bp),             accr);
      accz = mfma16(a, *(const bf16x8*)(bp + 256 * 512), accz);
    }
    #pragma unroll
    for (int ks = 0; ks < 8; ++ks) {
      bf16x8 a = *(const bf16x8*)(Ab + 256 + ks * 32);
      accdh = mfma16(a, *(const bf16x8*)(P2T + (long)c * 256 + ks * 32 + quad * 8), accdh);
      accg  = mfma16(a, *(const bf16x8*)(P1T + (w * 16 + n16) * 256 + ks * 32 + quad * 8), accg);
    }

    // ---- S3: r,z gates; publish rh slice (packed u64: 4 bf16 rows per lane) ----
    float zv[4];
    {
      u64 pk = 0;
      #pragma unroll
      for (int r = 0; r < 4; ++r) {
        float rv = sigm(accr[r] + brz_r);
        pk |= (u64)bfbits(rv * hreg[r]) << (16 * r);
        zv[r] = sigm(accz[r] + brz_z);
      }
      __hip_atomic_store(rhx + ((long)(g * 256 + c)) * 4 + quad, pk,
                         __ATOMIC_RELAXED, __HIP_MEMORY_SCOPE_AGENT);
      #pragma unroll
      for (int r = 0; r < 4; ++r) gbuf[quad * 4 + r][w * 16 + n16] = accg[r] + c1v;
    }
    asm volatile("s_waitcnt vmcnt(0)" ::: "memory");
    __syncthreads();                                               // bar1
    if (tid == 64)
      __hip_atomic_fetch_add(rhF, 1u, __ATOMIC_RELAXED, __HIP_MEMORY_SCOPE_AGENT);

    // ---- S4: LayerNorm(G=32)+relu (tid<16); both waves: accn x-part (ks 0..7) ----
    if (tid < 16) {
      float mu = 0, s2 = 0;
      #pragma unroll
      for (int cc = 0; cc < 32; ++cc) { float v = gbuf[tid][cc]; mu += v; s2 += v * v; }
      mu *= (1.0f / 32.0f);
      s2 = s2 * (1.0f / 32.0f) - mu * mu;
      float rstd = rsqrtf(s2 + 1e-5f);
      #pragma unroll
      for (int cc = 0; cc < 32; ++cc) {
        float gn = (gbuf[tid][cc] - mu) * rstd * lngs[cc] + lnbs[cc];
        gact[tid][cc] = (bf16)fmaxf(gn, 0.0f);
      }
    }
    #pragma unroll
    for (int ks = 0; ks < 8; ++ks) {
      bf16x8 a = *(const bf16x8*)(Ab + ks * 32);
      accn = mfma16(a, *(const bf16x8*)(WnT + (long)c * 512 + ks * 32 + quad * 8), accn);
    }
    __syncthreads();                                               // bar2

    // ---- S5: g2 (wave 0) ; spin for partners' rh (one lane of wave 1) ----
    if (w == 0) {
      bf16x8 a = *(const bf16x8*)&gact[n16][quad * 8];
      f32x4 a0 = {}, a1 = {};
      a0 = mfma16(a, *(const bf16x8*)(g2T + n16 * 32 + quad * 8), a0);
      a1 = mfma16(a, *(const bf16x8*)(g2T + (16 + n16) * 32 + quad * 8), a1);
      #pragma unroll
      for (int r = 0; r < 4; ++r) {
        int row = quad * 4 + r;
        g2act[row][n16]      = (bf16)fmaxf(a0[r] + g2bv0, 0.0f);
        g2act[row][16 + n16] = (bf16)fmaxf(a1[r] + g2bv1, 0.0f);
      }
    }
    if (tid == 65) {
      const u32 tgt = 8u * (u32)(t + 1);
      while (__hip_atomic_load(rhF, __ATOMIC_RELAXED, __HIP_MEMORY_SCOPE_AGENT) < tgt) {}
    }
    __syncthreads();                                               // bar3

    // ---- S6a: g3 (K=32); read back full rh -> Abuf[:,256:512] ----
    f32x4 acce = {}, acct = {}, acca = {};
    {
      bf16x8 a3 = *(const bf16x8*)&g2act[n16][quad * 8];
      const bf16* bp3 = g3T + (long)c * 32 + quad * 8;
      acce = mfma16(a3, *(const bf16x8*)(bp3),            acce);
      acct = mfma16(a3, *(const bf16x8*)(bp3 + 256 * 32), acct);
      acca = mfma16(a3, *(const bf16x8*)(bp3 + 512 * 32), acca);
    }
    {
      #pragma unroll
      for (int it = 0; it < 2; ++it) {
        int cc = tid + it * 128;
        const u64* rp = rhx + ((long)(g * 256 + cc)) * 4;
        #pragma unroll
        for (int j = 0; j < 4; ++j) {
          u64 v = __hip_atomic_load(rp + j, __ATOMIC_RELAXED, __HIP_MEMORY_SCOPE_AGENT);
          #pragma unroll
          for (int r = 0; r < 4; ++r)
            *(u16*)&Abuf[j * 4 + r][256 + cc] = (u16)(v >> (16 * r));
        }
      }
    }
    __syncthreads();                                               // bar4

    // ---- S6b: accn rh-part (ks 8..15) ----
    #pragma unroll
    for (int ks = 8; ks < 16; ++ks) {
      bf16x8 a = *(const bf16x8*)(Ab + ks * 32);
      accn = mfma16(a, *(const bf16x8*)(WnT + (long)c * 512 + ks * 32 + quad * 8), accn);
    }

    // ---- S7: h update; publish h slice via out (agent-scope stores) ----
    {
      float* op = out + ((long)(b0 + quad * 4) * 256 + t) * 256 + c;
      #pragma unroll
      for (int r = 0; r < 4; ++r) {
        float hv  = hreg[r];
        float dh  = accdh[r] + c2v;
        float eta = sigm(acce[r] + bg3e);
        float th  = fminf(softplus_(acct[r] + bg3t), 5.0f);
        float al  = sigm(acca[r] + bg3a) * scale;
        float nn  = tanh_(accn[r] + bwn);
        float s   = fminf(fmaxf(eta * hv - th * dh, -5.0f), 5.0f);
        float htl = (1.0f - al) * hv + al * s;
        float hn  = zv[r] * htl + (1.0f - zv[r]) * nn;
        hreg[r] = hn;
        __hip_atomic_store(op + (long)r * 65536, hn,
                           __ATOMIC_RELAXED, __HIP_MEMORY_SCOPE_AGENT);
      }
    }
    asm volatile("s_waitcnt vmcnt(0)" ::: "memory");
    __syncthreads();                                               // bar5
    if (tid == 64 && notlast)
      __hip_atomic_fetch_add(hF, 1u, __ATOMIC_RELAXED, __HIP_MEMORY_SCOPE_AGENT);

    // stage x_{t+1} into Abuf from prefetch regs; overlap h-spin
    if (notlast) {
      #pragma unroll
      for (int k = 0; k < 4; ++k) {
        bf16x8 v;
        #pragma unroll
        for (int j = 0; j < 4; ++j) { v[j] = (bf16)xr[2 * k][j]; v[4 + j] = (bf16)xr[2 * k + 1][j]; }
        *(bf16x8*)&Abuf[srow][scol + k * 8] = v;
      }
      if (tid == 65) {
        const u32 tgt = 8u * (u32)(t + 1);
        while (__hip_atomic_load(hF, __ATOMIC_RELAXED, __HIP_MEMORY_SCOPE_AGENT) < tgt) {}
      }
    }
    __syncthreads();                                               // bar6

    // read back full h_t (fp32 from out, via MALL) -> Abuf[:,256:512]
    if (notlast) {
      const u64* hp = (const u64*)(out + ((long)(b0 + srow) * 256 + t) * 256 + scol);
      #pragma unroll
      for (int k = 0; k < 4; ++k) {
        bf16x8 o;
        #pragma unroll
        for (int j = 0; j < 4; ++j) {
          u64 v = __hip_atomic_load(hp + 4 * k + j, __ATOMIC_RELAXED, __HIP_MEMORY_SCOPE_AGENT);
          o[2 * j]     = (bf16)__builtin_bit_cast(float, (u32)(v & 0xffffffffull));
          o[2 * j + 1] = (bf16)__builtin_bit_cast(float, (u32)(v >> 32));
        }
        *(bf16x8*)&Abuf[srow][256 + scol + k * 8] = o;
      }
    }
    __syncthreads();                                               // bar7
  }
}

// ---------------- launch ----------------

extern "C" void kernel_launch(void* const* d_in, const int* in_sizes, int n_in,
                              void* d_out, int out_size, void* d_ws, size_t ws_size,
                              hipStream_t stream) {
  const float* obs    = (const float*)d_in[0];
  const float* h0     = (const float*)d_in[1];
  const int*   epoch  = (const int*)  d_in[2];
  const float* obs_W  = (const float*)d_in[3];
  const float* obs_b  = (const float*)d_in[4];
  const float* enc_W  = (const float*)d_in[5];
  const float* enc_b  = (const float*)d_in[6];
  const float* pre_W  = (const float*)d_in[7];
  const float* pre_b  = (const float*)d_in[8];
  const float* pred_W = (const float*)d_in[9];
  const float* pred_b = (const float*)d_in[10];
  const float* Wrz_W  = (const float*)d_in[11];
  const float* Wrz_b  = (const float*)d_in[12];
  const float* Wn_W   = (const float*)d_in[13];
  const float* Wn_b   = (const float*)d_in[14];
  const float* g1_W   = (const float*)d_in[15];
  const float* g1_b   = (const float*)d_in[16];
  const float* ln_g   = (const float*)d_in[17];
  const float* ln_b   = (const float*)d_in[18];
  const float* g2_W   = (const float*)d_in[19];
  const float* g2_b   = (const float*)d_in[20];
  const float* g3_W   = (const float*)d_in[21];
  const float* g3_b   = (const float*)d_in[22];
  const float* dp_W   = (const float*)d_in[23];

  bf16* W = (bf16*)d_ws;
  bf16* WrzT  = W + 0;        // 262144 elems
  bf16* WnT   = W + 262144;   // 131072
  bf16* P2T   = W + 393216;   // 65536
  bf16* P1T   = W + 458752;   // 8192
  bf16* g2T   = W + 466944;   // 1024
  bf16* g3T   = W + 467968;   // 24576
  bf16* obsWT = W + 492544;   // 16384
  bf16* encWT = W + 508928;   // 65536
  bf16* preWT = W + 574464;   // 65536  -> weights end at byte 1280000
  float* c2f  = (float*)((char*)d_ws + 1280000);  // 256 f32
  float* c1f  = (float*)((char*)d_ws + 1281024);  // 32 f32
  u64*  rhx   = (u64*) ((char*)d_ws + 1281152);   // 64*256*4 u64 = 524288 B
  u32*  rhfl  = (u32*) ((char*)d_ws + 1805440);   // 64 groups * 16 u32 = 4096 B
  u32*  hfl   = (u32*) ((char*)d_ws + 1809536);   // 4096 B (contiguous after rhfl)
  float* out = (float*)d_out;

  k_zero<<<8, 256, 0, stream>>>(rhfl, 2048);      // zero both flag arrays

  k_transpose<<<1024, 256, 0, stream>>>(Wrz_W, WrzT, 512, 512);
  k_transpose<<<512,  256, 0, stream>>>(Wn_W,  WnT,  512, 256);
  k_transpose<<<4,    256, 0, stream>>>(g2_W,  g2T,  32,  32);
  k_transpose<<<96,   256, 0, stream>>>(g3_W,  g3T,  32,  768);
  k_transpose<<<64,   256, 0, stream>>>(obs_W, obsWT, 64, 256);
  k_transpose<<<256,  256, 0, stream>>>(enc_W, encWT, 256, 256);
  k_transpose<<<256,  256, 0, stream>>>(pre_W, preWT, 256, 256);
  k_p2<<<256, 256, 0, stream>>>(pred_W, dp_W, P2T);
  k_p1<<<32,  256, 0, stream>>>(pred_W, g1_W, P1T);
  k_cvec<<<1, 256, 0, stream>>>(pred_b, dp_W, g1_W, g1_b, c2f, c1f);

  k_phase1<<<4096, 256, 0, stream>>>(obs, obsWT, encWT, preWT, obs_b, enc_b, pre_b, out);
  k_phase2<<<512, 128, 0, stream>>>(h0, epoch, out, WrzT, WnT, P2T, P1T, g2T, g3T,
                                    c2f, c1f, Wrz_b, Wn_b, g2_b, g3_b, ln_g, ln_b,
                                    rhx, rhfl, hfl);

  (void)in_sizes; (void)n_in; (void)out_size; (void)ws_size;
}

// Round 3
// 2368.636 us; speedup vs baseline: 2.2166x; 2.2166x over previous
//
#include <hip/hip_runtime.h>

typedef __bf16 bf16;
typedef __bf16 bf16x8 __attribute__((ext_vector_type(8)));
typedef float  f32x4  __attribute__((ext_vector_type(4)));
typedef unsigned int       u32;
typedef unsigned short     u16;
typedef unsigned long long u64;

__device__ __forceinline__ f32x4 mfma16(bf16x8 a, bf16x8 b, f32x4 c) {
  return __builtin_amdgcn_mfma_f32_16x16x32_bf16(a, b, c, 0, 0, 0);
}
__device__ __forceinline__ float sigm(float x)  { return 1.0f / (1.0f + __expf(-x)); }
__device__ __forceinline__ float tanh_(float x) { return 2.0f / (1.0f + __expf(-2.0f * x)) - 1.0f; }
__device__ __forceinline__ float softplus_(float x) {
  return fmaxf(x, 0.0f) + __logf(1.0f + __expf(-fabsf(x)));
}
__device__ __forceinline__ float leaky_(float x) { return x > 0.0f ? x : 0.01f * x; }
__device__ __forceinline__ u16 bfbits(float f) { return __builtin_bit_cast(u16, (bf16)f); }

// ---------------- prep kernels (fp32 in -> bf16 out) ----------------

__global__ void k_transpose(const float* __restrict__ src, bf16* __restrict__ dst, int K, int N) {
  int i = blockIdx.x * 256 + threadIdx.x;
  if (i < K * N) { int k = i / N; int n = i - k * N; dst[n * K + k] = (bf16)src[i]; }
}

__global__ void k_p2(const float* __restrict__ pred, const float* __restrict__ dp, bf16* __restrict__ P2T) {
  int i = blockIdx.x * 256 + threadIdx.x;   // 65536
  int irow = i >> 8, n = i & 255;
  float acc = 0.0f;
  for (int j = 0; j < 256; ++j) {
    float p = pred[irow * 256 + j] - (j == irow ? 1.0f : 0.0f);
    acc += p * dp[j * 256 + n];
  }
  P2T[n * 256 + irow] = (bf16)acc;
}

__global__ void k_p1(const float* __restrict__ pred, const float* __restrict__ g1, bf16* __restrict__ P1T) {
  int i = blockIdx.x * 256 + threadIdx.x;   // 8192
  int irow = i >> 5, n = i & 31;
  float acc = 0.0f;
  for (int j = 0; j < 256; ++j) {
    float p = pred[irow * 256 + j] - (j == irow ? 1.0f : 0.0f);
    acc += p * g1[j * 32 + n];
  }
  P1T[n * 256 + irow] = (bf16)acc;
}

__global__ void k_cvec(const float* __restrict__ pred_b, const float* __restrict__ dp,
                       const float* __restrict__ g1, const float* __restrict__ g1_b,
                       float* __restrict__ c2f, float* __restrict__ c1f) {
  int n = threadIdx.x;  // 256 threads
  float acc = 0.0f;
  for (int j = 0; j < 256; ++j) acc += pred_b[j] * dp[j * 256 + n];
  c2f[n] = acc;
  if (n < 32) {
    float a2 = 0.0f;
    for (int j = 0; j < 256; ++j) a2 += pred_b[j] * g1[j * 32 + n];
    c1f[n] = a2 + g1_b[n];
  }
}

__global__ void k_zero(u32* __restrict__ p, int n) {
  int i = blockIdx.x * 256 + threadIdx.x;
  if (i < n) p[i] = 0;
}

// ---------------- phase 1: x = leaky(leaky(LN(obs@obs_W+b))@enc_W+b)@pre_W+b) ----------------

__global__ __launch_bounds__(256, 2) void k_phase1(
    const float* __restrict__ obs,
    const bf16* __restrict__ obs_WT, const bf16* __restrict__ enc_WT, const bf16* __restrict__ pre_WT,
    const float* __restrict__ obs_b, const float* __restrict__ enc_b, const float* __restrict__ pre_b,
    float* __restrict__ out)
{
  const int tid  = threadIdx.x;
  const int lane = tid & 63;
  const int w    = tid >> 6;       // wave 0..3
  const int n16  = lane & 15, quad = lane >> 4;
  const long R0  = (long)blockIdx.x * 64;

  __shared__ __align__(16) bf16 obsb[64][72];
  __shared__ __align__(16) bf16 ebuf[64][264];
  __shared__ __align__(16) bf16 e2buf[64][264];
  __shared__ float red[64][8];

  { // load obs tile 64x64 (fp32 -> bf16)
    int row = tid >> 2, col = (tid & 3) * 16;
    const float* src = obs + (R0 + row) * 64 + col;
    #pragma unroll
    for (int q = 0; q < 16; ++q) obsb[row][col + q] = (bf16)src[q];
  }
  __syncthreads();

  // G1: e0 = obs @ obs_W + obs_b  (K=64)
  {
    f32x4 acc[4][4] = {};
    #pragma unroll
    for (int ks = 0; ks < 2; ++ks) {
      bf16x8 a[4];
      #pragma unroll
      for (int mt = 0; mt < 4; ++mt) a[mt] = *(const bf16x8*)&obsb[mt * 16 + n16][ks * 32 + quad * 8];
      #pragma unroll
      for (int nt = 0; nt < 4; ++nt) {
        int ncol = (4 * w + nt) * 16 + n16;
        bf16x8 b = *(const bf16x8*)(obs_WT + ncol * 64 + ks * 32 + quad * 8);
        #pragma unroll
        for (int mt = 0; mt < 4; ++mt) acc[mt][nt] = mfma16(a[mt], b, acc[mt][nt]);
      }
    }
    #pragma unroll
    for (int nt = 0; nt < 4; ++nt) {
      int ncol = (4 * w + nt) * 16 + n16;
      float bb = obs_b[ncol];
      #pragma unroll
      for (int mt = 0; mt < 4; ++mt)
        #pragma unroll
        for (int reg = 0; reg < 4; ++reg)
          ebuf[mt * 16 + quad * 4 + reg][ncol] = (bf16)(acc[mt][nt][reg] + bb);
    }
  }
  __syncthreads();
  // LayerNorm over 256 (no affine)
  {
    int row = tid >> 2, qt = tid & 3;
    float s = 0, s2 = 0;
    for (int c = 0; c < 64; ++c) { float v = (float)ebuf[row][qt * 64 + c]; s += v; s2 += v * v; }
    red[row][qt] = s; red[row][4 + qt] = s2;
  }
  __syncthreads();
  if (tid < 64) {
    float s  = red[tid][0] + red[tid][1] + red[tid][2] + red[tid][3];
    float s2 = red[tid][4] + red[tid][5] + red[tid][6] + red[tid][7];
    float mu = s * (1.0f / 256.0f);
    float var = s2 * (1.0f / 256.0f) - mu * mu;
    red[tid][0] = mu; red[tid][1] = rsqrtf(var + 1e-5f);
  }
  __syncthreads();
  {
    int row = tid >> 2, qt = tid & 3;
    float mu = red[row][0], rstd = red[row][1];
    for (int c = 0; c < 64; ++c) {
      int cc = qt * 64 + c;
      ebuf[row][cc] = (bf16)(((float)ebuf[row][cc] - mu) * rstd);
    }
  }
  __syncthreads();
  // G2: e1 = leaky(e0n @ enc_W + enc_b)
  {
    f32x4 acc[4][4] = {};
    #pragma unroll
    for (int ks = 0; ks < 8; ++ks) {
      bf16x8 a[4];
      #pragma unroll
      for (int mt = 0; mt < 4; ++mt) a[mt] = *(const bf16x8*)&ebuf[mt * 16 + n16][ks * 32 + quad * 8];
      #pragma unroll
      for (int nt = 0; nt < 4; ++nt) {
        int ncol = (4 * w + nt) * 16 + n16;
        bf16x8 b = *(const bf16x8*)(enc_WT + ncol * 256 + ks * 32 + quad * 8);
        #pragma unroll
        for (int mt = 0; mt < 4; ++mt) acc[mt][nt] = mfma16(a[mt], b, acc[mt][nt]);
      }
    }
    #pragma unroll
    for (int nt = 0; nt < 4; ++nt) {
      int ncol = (4 * w + nt) * 16 + n16;
      float bb = enc_b[ncol];
      #pragma unroll
      for (int mt = 0; mt < 4; ++mt)
        #pragma unroll
        for (int reg = 0; reg < 4; ++reg)
          e2buf[mt * 16 + quad * 4 + reg][ncol] = (bf16)leaky_(acc[mt][nt][reg] + bb);
    }
  }
  __syncthreads();
  // G3: x = leaky(e1 @ pre_W + pre_b) -> global fp32 (d_out doubles as x buffer)
  {
    f32x4 acc[4][4] = {};
    #pragma unroll
    for (int ks = 0; ks < 8; ++ks) {
      bf16x8 a[4];
      #pragma unroll
      for (int mt = 0; mt < 4; ++mt) a[mt] = *(const bf16x8*)&e2buf[mt * 16 + n16][ks * 32 + quad * 8];
      #pragma unroll
      for (int nt = 0; nt < 4; ++nt) {
        int ncol = (4 * w + nt) * 16 + n16;
        bf16x8 b = *(const bf16x8*)(pre_WT + ncol * 256 + ks * 32 + quad * 8);
        #pragma unroll
        for (int mt = 0; mt < 4; ++mt) acc[mt][nt] = mfma16(a[mt], b, acc[mt][nt]);
      }
    }
    #pragma unroll
    for (int nt = 0; nt < 4; ++nt) {
      int ncol = (4 * w + nt) * 16 + n16;
      float bb = pre_b[ncol];
      #pragma unroll
      for (int mt = 0; mt < 4; ++mt)
        #pragma unroll
        for (int reg = 0; reg < 4; ++reg)
          out[(R0 + mt * 16 + quad * 4 + reg) * 256 + ncol] = leaky_(acc[mt][nt][reg] + bb);
    }
  }
}

// ---------------- phase 2: column-split persistent scan, K-split wave pairs ----------------
// 256 wgs x 512 thr (8 waves, 2 per SIMD). Group g = bid>>2 owns rows 16g..16g+15;
// quarter q = bid&3 owns h-cols [64q,64q+64). Waves (wlow, wlow+4) both own col
// c = 64q+16*wlow+n16 and split every GEMM's K range (hi = K-half); partials are
// pair-reduced via LDS. Loop is reordered so the h-exchange RTT hides under the
// next step's x-part GEMMs and the rh RTT hides under LN+g2.
// Exchange protocol identical to the verified Q=4 version (4 publishers/group).

__global__ __launch_bounds__(512, 1) void k_phase2(
    const float* __restrict__ h0,
    const int*  __restrict__ epoch_p,
    float* __restrict__ out,
    const bf16* __restrict__ WrzT, const bf16* __restrict__ WnT,
    const bf16* __restrict__ P2T,  const bf16* __restrict__ P1T,
    const bf16* __restrict__ g2T,  const bf16* __restrict__ g3T,
    const float* __restrict__ c2f, const float* __restrict__ c1f,
    const float* __restrict__ Wrz_b, const float* __restrict__ Wn_b,
    const float* __restrict__ g2_b,  const float* __restrict__ g3_b,
    const float* __restrict__ ln_g,  const float* __restrict__ ln_b,
    u64* __restrict__ rhx, u32* __restrict__ rhflag, u32* __restrict__ hflag)
{
  const int tid  = threadIdx.x;
  const int lane = tid & 63;
  const int w    = tid >> 6;        // wave 0..7
  const int wlow = w & 3;           // col-set owner
  const int hi   = w >> 2;          // K-half
  const int n16  = lane & 15;
  const int quad = lane >> 4;
  const int g    = blockIdx.x >> 2; // batch group 0..63
  const int q    = blockIdx.x & 3;  // column quarter 0..3
  const int b0   = g * 16;
  const int c    = q * 64 + wlow * 16 + n16;   // own global h-col

  __shared__ __align__(16) bf16  Abuf[16][520];   // [x_t | h-then-rh]
  __shared__ __align__(16) float gbuf[16][36];
  __shared__ __align__(16) bf16  gact[16][40];
  __shared__ __align__(16) bf16  g2act[16][40];
  __shared__ float red[4][64][17];                // hi1 partials, pad 17 (bank-safe)
  __shared__ float lngs[32], lnbs[32];

  if (tid < 32) { lngs[tid] = ln_g[tid]; lnbs[tid] = ln_b[tid]; }

  const int ep = *epoch_p;
  const float scale = fminf(1.0f, fmaxf(0.0f, ((float)ep - 5.0f) / 40.0f));

  const float brz_r = Wrz_b[c];
  const float brz_z = Wrz_b[256 + c];
  const float bwn   = Wn_b[c];
  const float bg3e  = g3_b[c];
  const float bg3t  = g3_b[256 + c];
  const float bg3a  = g3_b[512 + c];
  const float c2v   = c2f[c];
  const float c1v   = (wlow < 2) ? c1f[wlow * 16 + n16] : 0.0f;
  const float g2bv0 = g2_b[n16];
  const float g2bv1 = g2_b[16 + n16];

  // own-column fp32 h state (hi0 lanes authoritative)
  float hreg[4];
  #pragma unroll
  for (int r = 0; r < 4; ++r)
    hreg[r] = h0[(long)(b0 + quad * 4 + r) * 256 + c];

  const int srow = tid >> 5;          // 0..15
  const int scol = (tid & 31) * 8;    // 0..248

  { // stage x_0 and full h0 (bf16) into Abuf (8 cols per thread)
    const float* hp = h0 + (long)(b0 + srow) * 256 + scol;
    const float* xp = out + ((long)(b0 + srow) * 256 + 0) * 256 + scol;
    bf16x8 xv, hv;
    #pragma unroll
    for (int j = 0; j < 8; ++j) { xv[j] = (bf16)xp[j]; hv[j] = (bf16)hp[j]; }
    *(bf16x8*)&Abuf[srow][scol]       = xv;
    *(bf16x8*)&Abuf[srow][256 + scol] = hv;
  }
  __syncthreads();

  const bf16* Ab = &Abuf[n16][quad * 8];
  u32* rhF = rhflag + g * 16;
  u32* hF  = hflag  + g * 16;
  const int k0 = hi * 4;              // this wave's K-quarter base

  for (int t = 0; t < 256; ++t) {
    const bool notlast = (t < 255);

    // prefetch x_{t+1} (8 f32/thread; staged at S2)
    f32x4 xr0 = {}, xr1 = {};
    if (notlast) {
      const float* xp = out + ((long)(b0 + srow) * 256 + (t + 1)) * 256 + scol;
      xr0 = *(const f32x4*)(xp);
      xr1 = *(const f32x4*)(xp + 4);
    }

    // ---- S1: x-part GEMMs (run in the h-exchange RTT shadow) ----
    f32x4 accr = {}, accz = {}, accn = {}, accdh = {}, accg = {};
    #pragma unroll
    for (int ks = 0; ks < 4; ++ks) {
      const int kk = k0 + ks;                       // 0..3 / 4..7
      bf16x8 a = *(const bf16x8*)(Ab + kk * 32);
      const bf16* bp = WrzT + (long)c * 512 + kk * 32 + quad * 8;
      accr = mfma16(a, *(const bf16x8*)(bp),             accr);
      accz = mfma16(a, *(const bf16x8*)(bp + 256 * 512), accz);
      accn = mfma16(a, *(const bf16x8*)(WnT + (long)c * 512 + kk * 32 + quad * 8), accn);
    }

    // ---- S2: h_t readback + x_{t+1} staging ----
    if (t > 0 && tid == 320) {
      const u32 tgt = 4u * (u32)t;
      while (__hip_atomic_load(hF, __ATOMIC_RELAXED, __HIP_MEMORY_SCOPE_AGENT) < tgt) {}
    }
    __syncthreads();                                               // bar A
    if (t > 0) {
      const u64* hp = (const u64*)(out + ((long)(b0 + srow) * 256 + (t - 1)) * 256 + scol);
      bf16x8 o;
      #pragma unroll
      for (int j = 0; j < 4; ++j) {
        u64 v = __hip_atomic_load(hp + j, __ATOMIC_RELAXED, __HIP_MEMORY_SCOPE_AGENT);
        o[2 * j]     = (bf16)__builtin_bit_cast(float, (u32)(v & 0xffffffffull));
        o[2 * j + 1] = (bf16)__builtin_bit_cast(float, (u32)(v >> 32));
      }
      *(bf16x8*)&Abuf[srow][256 + scol] = o;
    }
    if (notlast) {
      bf16x8 v;
      #pragma unroll
      for (int j = 0; j < 4; ++j) { v[j] = (bf16)xr0[j]; v[4 + j] = (bf16)xr1[j]; }
      *(bf16x8*)&Abuf[srow][scol] = v;
    }
    __syncthreads();                                               // bar B

    // ---- S3: h-part GEMMs ----
    #pragma unroll
    for (int ks = 0; ks < 4; ++ks) {
      const int kk = 8 + k0 + ks;                   // 8..11 / 12..15
      bf16x8 a = *(const bf16x8*)(Ab + kk * 32);
      const bf16* bp = WrzT + (long)c * 512 + kk * 32 + quad * 8;
      accr = mfma16(a, *(const bf16x8*)(bp),             accr);
      accz = mfma16(a, *(const bf16x8*)(bp + 256 * 512), accz);
    }
    #pragma unroll
    for (int ks = 0; ks < 4; ++ks) {
      const int kk = k0 + ks;
      bf16x8 a = *(const bf16x8*)(Ab + 256 + kk * 32);
      accdh = mfma16(a, *(const bf16x8*)(P2T + (long)c * 256 + kk * 32 + quad * 8), accdh);
      if (wlow < 2)
        accg = mfma16(a, *(const bf16x8*)(P1T + (wlow * 16 + n16) * 256 + kk * 32 + quad * 8), accg);
    }

    // ---- R1: pair-reduce accr, accg (hi1 -> LDS) ----
    if (hi) {
      #pragma unroll
      for (int r = 0; r < 4; ++r) red[wlow][lane][r] = accr[r];
      if (wlow < 2) {
        #pragma unroll
        for (int r = 0; r < 4; ++r) red[wlow][lane][4 + r] = accg[r];
      }
    }
    __syncthreads();                                               // bar C

    // ---- S4: r gate; publish rh; gbuf (hi0 only) ----
    if (!hi) {
      u64 pk = 0;
      #pragma unroll
      for (int r = 0; r < 4; ++r) {
        float rv = sigm(accr[r] + red[wlow][lane][r] + brz_r);
        pk |= (u64)bfbits(rv * hreg[r]) << (16 * r);
      }
      __hip_atomic_store(rhx + ((long)(g * 256 + c)) * 4 + quad, pk,
                         __ATOMIC_RELAXED, __HIP_MEMORY_SCOPE_AGENT);
      if (wlow < 2) {
        #pragma unroll
        for (int r = 0; r < 4; ++r)
          gbuf[quad * 4 + r][wlow * 16 + n16] = accg[r] + red[wlow][lane][4 + r] + c1v;
      }
    }
    asm volatile("s_waitcnt vmcnt(0)" ::: "memory");
    __syncthreads();                                               // bar D
    if (tid == 256)
      __hip_atomic_fetch_add(rhF, 1u, __ATOMIC_RELAXED, __HIP_MEMORY_SCOPE_AGENT);

    // ---- S5: LN + g2 (rh RTT shadow) ----
    if (tid < 16) {
      float mu = 0, s2 = 0;
      #pragma unroll
      for (int cc = 0; cc < 32; ++cc) { float v = gbuf[tid][cc]; mu += v; s2 += v * v; }
      mu *= (1.0f / 32.0f);
      s2 = s2 * (1.0f / 32.0f) - mu * mu;
      float rstd = rsqrtf(s2 + 1e-5f);
      #pragma unroll
      for (int cc = 0; cc < 32; ++cc) {
        float gn = (gbuf[tid][cc] - mu) * rstd * lngs[cc] + lnbs[cc];
        gact[tid][cc] = (bf16)fmaxf(gn, 0.0f);
      }
    }
    __syncthreads();                                               // bar E
    if (w == 0) {
      bf16x8 a = *(const bf16x8*)&gact[n16][quad * 8];
      f32x4 a0 = {}, a1 = {};
      a0 = mfma16(a, *(const bf16x8*)(g2T + n16 * 32 + quad * 8), a0);
      a1 = mfma16(a, *(const bf16x8*)(g2T + (16 + n16) * 32 + quad * 8), a1);
      #pragma unroll
      for (int r = 0; r < 4; ++r) {
        int row = quad * 4 + r;
        g2act[row][n16]      = (bf16)fmaxf(a0[r] + g2bv0, 0.0f);
        g2act[row][16 + n16] = (bf16)fmaxf(a1[r] + g2bv1, 0.0f);
      }
    }
    if (tid == 320) {
      const u32 tgt = 4u * (u32)(t + 1);
      while (__hip_atomic_load(rhF, __ATOMIC_RELAXED, __HIP_MEMORY_SCOPE_AGENT) < tgt) {}
    }
    __syncthreads();                                               // bar F

    // ---- S6: rh readback -> Abuf[:,256:512] (2 u64 per thread) ----
    {
      const int cc = tid >> 1;
      const int jb = (tid & 1) * 2;
      const u64* rp = rhx + ((long)(g * 256 + cc)) * 4 + jb;
      #pragma unroll
      for (int jj = 0; jj < 2; ++jj) {
        u64 v = __hip_atomic_load(rp + jj, __ATOMIC_RELAXED, __HIP_MEMORY_SCOPE_AGENT);
        #pragma unroll
        for (int r = 0; r < 4; ++r)
          *(u16*)&Abuf[(jb + jj) * 4 + r][256 + cc] = (u16)(v >> (16 * r));
      }
    }
    __syncthreads();                                               // bar G

    // ---- S7: accn rh-part; g3 (hi0) ----
    #pragma unroll
    for (int ks = 0; ks < 4; ++ks) {
      const int kk = 8 + k0 + ks;
      bf16x8 a = *(const bf16x8*)(Ab + kk * 32);
      accn = mfma16(a, *(const bf16x8*)(WnT + (long)c * 512 + kk * 32 + quad * 8), accn);
    }
    f32x4 acce = {}, acct = {}, acca = {};
    if (!hi) {
      bf16x8 a3 = *(const bf16x8*)&g2act[n16][quad * 8];
      const bf16* bp3 = g3T + (long)c * 32 + quad * 8;
      acce = mfma16(a3, *(const bf16x8*)(bp3),            acce);
      acct = mfma16(a3, *(const bf16x8*)(bp3 + 256 * 32), acct);
      acca = mfma16(a3, *(const bf16x8*)(bp3 + 512 * 32), acca);
    }
    // R2: pair-reduce accz, accdh, accn (hi1 -> LDS)
    if (hi) {
      #pragma unroll
      for (int r = 0; r < 4; ++r) {
        red[wlow][lane][r]     = accz[r];
        red[wlow][lane][4 + r] = accdh[r];
        red[wlow][lane][8 + r] = accn[r];
      }
    }
    __syncthreads();                                               // bar H

    // ---- S8: h update + publish (hi0) ----
    if (!hi) {
      float* op = out + ((long)(b0 + quad * 4) * 256 + t) * 256 + c;
      #pragma unroll
      for (int r = 0; r < 4; ++r) {
        float hv  = hreg[r];
        float zf  = sigm(accz[r] + red[wlow][lane][r] + brz_z);
        float dh  = accdh[r] + red[wlow][lane][4 + r] + c2v;
        float nn  = tanh_(accn[r] + red[wlow][lane][8 + r] + bwn);
        float eta = sigm(acce[r] + bg3e);
        float th  = fminf(softplus_(acct[r] + bg3t), 5.0f);
        float al  = sigm(acca[r] + bg3a) * scale;
        float s   = fminf(fmaxf(eta * hv - th * dh, -5.0f), 5.0f);
        float htl = (1.0f - al) * hv + al * s;
        float hn  = zf * htl + (1.0f - zf) * nn;
        hreg[r] = hn;
        __hip_atomic_store(op + (long)r * 65536, hn,
                           __ATOMIC_RELAXED, __HIP_MEMORY_SCOPE_AGENT);
      }
    }
    asm volatile("s_waitcnt vmcnt(0)" ::: "memory");
    __syncthreads();                                               // bar I
    if (tid == 256 && notlast)
      __hip_atomic_fetch_add(hF, 1u, __ATOMIC_RELAXED, __HIP_MEMORY_SCOPE_AGENT);
  }
}

// ---------------- launch ----------------

extern "C" void kernel_launch(void* const* d_in, const int* in_sizes, int n_in,
                              void* d_out, int out_size, void* d_ws, size_t ws_size,
                              hipStream_t stream) {
  const float* obs    = (const float*)d_in[0];
  const float* h0     = (const float*)d_in[1];
  const int*   epoch  = (const int*)  d_in[2];
  const float* obs_W  = (const float*)d_in[3];
  const float* obs_b  = (const float*)d_in[4];
  const float* enc_W  = (const float*)d_in[5];
  const float* enc_b  = (const float*)d_in[6];
  const float* pre_W  = (const float*)d_in[7];
  const float* pre_b  = (const float*)d_in[8];
  const float* pred_W = (const float*)d_in[9];
  const float* pred_b = (const float*)d_in[10];
  const float* Wrz_W  = (const float*)d_in[11];
  const float* Wrz_b  = (const float*)d_in[12];
  const float* Wn_W   = (const float*)d_in[13];
  const float* Wn_b   = (const float*)d_in[14];
  const float* g1_W   = (const float*)d_in[15];
  const float* g1_b   = (const float*)d_in[16];
  const float* ln_g   = (const float*)d_in[17];
  const float* ln_b   = (const float*)d_in[18];
  const float* g2_W   = (const float*)d_in[19];
  const float* g2_b   = (const float*)d_in[20];
  const float* g3_W   = (const float*)d_in[21];
  const float* g3_b   = (const float*)d_in[22];
  const float* dp_W   = (const float*)d_in[23];

  bf16* W = (bf16*)d_ws;
  bf16* WrzT  = W + 0;        // 262144 elems
  bf16* WnT   = W + 262144;   // 131072
  bf16* P2T   = W + 393216;   // 65536
  bf16* P1T   = W + 458752;   // 8192
  bf16* g2T   = W + 466944;   // 1024
  bf16* g3T   = W + 467968;   // 24576
  bf16* obsWT = W + 492544;   // 16384
  bf16* encWT = W + 508928;   // 65536
  bf16* preWT = W + 574464;   // 65536  -> weights end at byte 1280000
  float* c2f  = (float*)((char*)d_ws + 1280000);  // 256 f32
  float* c1f  = (float*)((char*)d_ws + 1281024);  // 32 f32
  u64*  rhx   = (u64*) ((char*)d_ws + 1281152);   // 64*256*4 u64 = 524288 B
  u32*  rhfl  = (u32*) ((char*)d_ws + 1805440);   // 64 groups * 16 u32 = 4096 B
  u32*  hfl   = (u32*) ((char*)d_ws + 1809536);   // 4096 B (contiguous after rhfl)
  float* out = (float*)d_out;

  k_zero<<<8, 256, 0, stream>>>(rhfl, 2048);      // zero both flag arrays

  k_transpose<<<1024, 256, 0, stream>>>(Wrz_W, WrzT, 512, 512);
  k_transpose<<<512,  256, 0, stream>>>(Wn_W,  WnT,  512, 256);
  k_transpose<<<4,    256, 0, stream>>>(g2_W,  g2T,  32,  32);
  k_transpose<<<96,   256, 0, stream>>>(g3_W,  g3T,  32,  768);
  k_transpose<<<64,   256, 0, stream>>>(obs_W, obsWT, 64, 256);
  k_transpose<<<256,  256, 0, stream>>>(enc_W, encWT, 256, 256);
  k_transpose<<<256,  256, 0, stream>>>(pre_W, preWT, 256, 256);
  k_p2<<<256, 256, 0, stream>>>(pred_W, dp_W, P2T);
  k_p1<<<32,  256, 0, stream>>>(pred_W, g1_W, P1T);
  k_cvec<<<1, 256, 0, stream>>>(pred_b, dp_W, g1_W, g1_b, c2f, c1f);

  k_phase1<<<4096, 256, 0, stream>>>(obs, obsWT, encWT, preWT, obs_b, enc_b, pre_b, out);
  k_phase2<<<256, 512, 0, stream>>>(h0, epoch, out, WrzT, WnT, P2T, P1T, g2T, g3T,
                                    c2f, c1f, Wrz_b, Wn_b, g2_b, g3_b, ln_g, ln_b,
                                    rhx, rhfl, hfl);

  (void)in_sizes; (void)n_in; (void)out_size; (void)ws_size;
}

// Round 4
// 2125.660 us; speedup vs baseline: 2.4700x; 1.1143x over previous
//
#include <hip/hip_runtime.h>

typedef __bf16 bf16;
typedef __bf16 bf16x8 __attribute__((ext_vector_type(8)));
typedef float  f32x4  __attribute__((ext_vector_type(4)));
typedef unsigned int       u32;
typedef unsigned short     u16;
typedef unsigned long long u64;

__device__ __forceinline__ f32x4 mfma16(bf16x8 a, bf16x8 b, f32x4 c) {
  return __builtin_amdgcn_mfma_f32_16x16x32_bf16(a, b, c, 0, 0, 0);
}
__device__ __forceinline__ float sigm(float x)  { return 1.0f / (1.0f + __expf(-x)); }
__device__ __forceinline__ float tanh_(float x) { return 2.0f / (1.0f + __expf(-2.0f * x)) - 1.0f; }
__device__ __forceinline__ float softplus_(float x) {
  return fmaxf(x, 0.0f) + __logf(1.0f + __expf(-fabsf(x)));
}
__device__ __forceinline__ float leaky_(float x) { return x > 0.0f ? x : 0.01f * x; }
__device__ __forceinline__ u16 bfbits(float f) { return __builtin_bit_cast(u16, (bf16)f); }

// ---------------- prep kernels (fp32 in -> bf16 out) ----------------

__global__ void k_transpose(const float* __restrict__ src, bf16* __restrict__ dst, int K, int N) {
  int i = blockIdx.x * 256 + threadIdx.x;
  if (i < K * N) { int k = i / N; int n = i - k * N; dst[n * K + k] = (bf16)src[i]; }
}

__global__ void k_p2(const float* __restrict__ pred, const float* __restrict__ dp, bf16* __restrict__ P2T) {
  int i = blockIdx.x * 256 + threadIdx.x;   // 65536
  int irow = i >> 8, n = i & 255;
  float acc = 0.0f;
  for (int j = 0; j < 256; ++j) {
    float p = pred[irow * 256 + j] - (j == irow ? 1.0f : 0.0f);
    acc += p * dp[j * 256 + n];
  }
  P2T[n * 256 + irow] = (bf16)acc;
}

__global__ void k_p1(const float* __restrict__ pred, const float* __restrict__ g1, bf16* __restrict__ P1T) {
  int i = blockIdx.x * 256 + threadIdx.x;   // 8192
  int irow = i >> 5, n = i & 31;
  float acc = 0.0f;
  for (int j = 0; j < 256; ++j) {
    float p = pred[irow * 256 + j] - (j == irow ? 1.0f : 0.0f);
    acc += p * g1[j * 32 + n];
  }
  P1T[n * 256 + irow] = (bf16)acc;
}

__global__ void k_cvec(const float* __restrict__ pred_b, const float* __restrict__ dp,
                       const float* __restrict__ g1, const float* __restrict__ g1_b,
                       float* __restrict__ c2f, float* __restrict__ c1f) {
  int n = threadIdx.x;  // 256 threads
  float acc = 0.0f;
  for (int j = 0; j < 256; ++j) acc += pred_b[j] * dp[j * 256 + n];
  c2f[n] = acc;
  if (n < 32) {
    float a2 = 0.0f;
    for (int j = 0; j < 256; ++j) a2 += pred_b[j] * g1[j * 32 + n];
    c1f[n] = a2 + g1_b[n];
  }
}

__global__ void k_zero(u32* __restrict__ p, int n) {
  int i = blockIdx.x * 256 + threadIdx.x;
  if (i < n) p[i] = 0;
}

// ---------------- phase 1: x = leaky(leaky(LN(obs@obs_W+b))@enc_W+b)@pre_W+b) ----------------

__global__ __launch_bounds__(256, 2) void k_phase1(
    const float* __restrict__ obs,
    const bf16* __restrict__ obs_WT, const bf16* __restrict__ enc_WT, const bf16* __restrict__ pre_WT,
    const float* __restrict__ obs_b, const float* __restrict__ enc_b, const float* __restrict__ pre_b,
    float* __restrict__ out)
{
  const int tid  = threadIdx.x;
  const int lane = tid & 63;
  const int w    = tid >> 6;       // wave 0..3
  const int n16  = lane & 15, quad = lane >> 4;
  const long R0  = (long)blockIdx.x * 64;

  __shared__ __align__(16) bf16 obsb[64][72];
  __shared__ __align__(16) bf16 ebuf[64][264];
  __shared__ __align__(16) bf16 e2buf[64][264];
  __shared__ float red[64][8];

  { // load obs tile 64x64 (fp32 -> bf16)
    int row = tid >> 2, col = (tid & 3) * 16;
    const float* src = obs + (R0 + row) * 64 + col;
    #pragma unroll
    for (int q = 0; q < 16; ++q) obsb[row][col + q] = (bf16)src[q];
  }
  __syncthreads();

  // G1: e0 = obs @ obs_W + obs_b  (K=64)
  {
    f32x4 acc[4][4] = {};
    #pragma unroll
    for (int ks = 0; ks < 2; ++ks) {
      bf16x8 a[4];
      #pragma unroll
      for (int mt = 0; mt < 4; ++mt) a[mt] = *(const bf16x8*)&obsb[mt * 16 + n16][ks * 32 + quad * 8];
      #pragma unroll
      for (int nt = 0; nt < 4; ++nt) {
        int ncol = (4 * w + nt) * 16 + n16;
        bf16x8 b = *(const bf16x8*)(obs_WT + ncol * 64 + ks * 32 + quad * 8);
        #pragma unroll
        for (int mt = 0; mt < 4; ++mt) acc[mt][nt] = mfma16(a[mt], b, acc[mt][nt]);
      }
    }
    #pragma unroll
    for (int nt = 0; nt < 4; ++nt) {
      int ncol = (4 * w + nt) * 16 + n16;
      float bb = obs_b[ncol];
      #pragma unroll
      for (int mt = 0; mt < 4; ++mt)
        #pragma unroll
        for (int reg = 0; reg < 4; ++reg)
          ebuf[mt * 16 + quad * 4 + reg][ncol] = (bf16)(acc[mt][nt][reg] + bb);
    }
  }
  __syncthreads();
  // LayerNorm over 256 (no affine)
  {
    int row = tid >> 2, qt = tid & 3;
    float s = 0, s2 = 0;
    for (int c = 0; c < 64; ++c) { float v = (float)ebuf[row][qt * 64 + c]; s += v; s2 += v * v; }
    red[row][qt] = s; red[row][4 + qt] = s2;
  }
  __syncthreads();
  if (tid < 64) {
    float s  = red[tid][0] + red[tid][1] + red[tid][2] + red[tid][3];
    float s2 = red[tid][4] + red[tid][5] + red[tid][6] + red[tid][7];
    float mu = s * (1.0f / 256.0f);
    float var = s2 * (1.0f / 256.0f) - mu * mu;
    red[tid][0] = mu; red[tid][1] = rsqrtf(var + 1e-5f);
  }
  __syncthreads();
  {
    int row = tid >> 2, qt = tid & 3;
    float mu = red[row][0], rstd = red[row][1];
    for (int c = 0; c < 64; ++c) {
      int cc = qt * 64 + c;
      ebuf[row][cc] = (bf16)(((float)ebuf[row][cc] - mu) * rstd);
    }
  }
  __syncthreads();
  // G2: e1 = leaky(e0n @ enc_W + enc_b)
  {
    f32x4 acc[4][4] = {};
    #pragma unroll
    for (int ks = 0; ks < 8; ++ks) {
      bf16x8 a[4];
      #pragma unroll
      for (int mt = 0; mt < 4; ++mt) a[mt] = *(const bf16x8*)&ebuf[mt * 16 + n16][ks * 32 + quad * 8];
      #pragma unroll
      for (int nt = 0; nt < 4; ++nt) {
        int ncol = (4 * w + nt) * 16 + n16;
        bf16x8 b = *(const bf16x8*)(enc_WT + ncol * 256 + ks * 32 + quad * 8);
        #pragma unroll
        for (int mt = 0; mt < 4; ++mt) acc[mt][nt] = mfma16(a[mt], b, acc[mt][nt]);
      }
    }
    #pragma unroll
    for (int nt = 0; nt < 4; ++nt) {
      int ncol = (4 * w + nt) * 16 + n16;
      float bb = enc_b[ncol];
      #pragma unroll
      for (int mt = 0; mt < 4; ++mt)
        #pragma unroll
        for (int reg = 0; reg < 4; ++reg)
          e2buf[mt * 16 + quad * 4 + reg][ncol] = (bf16)leaky_(acc[mt][nt][reg] + bb);
    }
  }
  __syncthreads();
  // G3: x = leaky(e1 @ pre_W + pre_b) -> global fp32 (d_out doubles as x buffer)
  {
    f32x4 acc[4][4] = {};
    #pragma unroll
    for (int ks = 0; ks < 8; ++ks) {
      bf16x8 a[4];
      #pragma unroll
      for (int mt = 0; mt < 4; ++mt) a[mt] = *(const bf16x8*)&e2buf[mt * 16 + n16][ks * 32 + quad * 8];
      #pragma unroll
      for (int nt = 0; nt < 4; ++nt) {
        int ncol = (4 * w + nt) * 16 + n16;
        bf16x8 b = *(const bf16x8*)(pre_WT + ncol * 256 + ks * 32 + quad * 8);
        #pragma unroll
        for (int mt = 0; mt < 4; ++mt) acc[mt][nt] = mfma16(a[mt], b, acc[mt][nt]);
      }
    }
    #pragma unroll
    for (int nt = 0; nt < 4; ++nt) {
      int ncol = (4 * w + nt) * 16 + n16;
      float bb = pre_b[ncol];
      #pragma unroll
      for (int mt = 0; mt < 4; ++mt)
        #pragma unroll
        for (int reg = 0; reg < 4; ++reg)
          out[(R0 + mt * 16 + quad * 4 + reg) * 256 + ncol] = leaky_(acc[mt][nt][reg] + bb);
    }
  }
}

// ---------------- phase 2: column-split persistent scan, K-split wave pairs ----------------
// Geometry as R2 (256 wgs x 512 thr, 8 waves = 2/SIMD, quarter q owns 64 cols,
// wave pair (wlow, wlow+4) K-splits every GEMM). NEW: the per-wave B-operands of
// the three big GEMMs (Wrz-r, Wrz-z, Wn) live in REGISTERS (24 bf16x8 = 96 VGPR,
// loaded once); P2/P1/g3/g2 slices live in LDS (staged once, bank-spread pitches).
// Per-step L2 weight streaming (~250 KB) is eliminated entirely.

__global__ __launch_bounds__(512, 2) void k_phase2(
    const float* __restrict__ h0,
    const int*  __restrict__ epoch_p,
    float* __restrict__ out,
    const bf16* __restrict__ WrzT, const bf16* __restrict__ WnT,
    const bf16* __restrict__ P2T,  const bf16* __restrict__ P1T,
    const bf16* __restrict__ g2T,  const bf16* __restrict__ g3T,
    const float* __restrict__ c2f, const float* __restrict__ c1f,
    const float* __restrict__ Wrz_b, const float* __restrict__ Wn_b,
    const float* __restrict__ g2_b,  const float* __restrict__ g3_b,
    const float* __restrict__ ln_g,  const float* __restrict__ ln_b,
    u64* __restrict__ rhx, u32* __restrict__ rhflag, u32* __restrict__ hflag)
{
  const int tid  = threadIdx.x;
  const int lane = tid & 63;
  const int w    = tid >> 6;        // wave 0..7
  const int wlow = w & 3;           // col-set owner
  const int hi   = w >> 2;          // K-half
  const int n16  = lane & 15;
  const int quad = lane >> 4;
  const int g    = blockIdx.x >> 2; // batch group 0..63
  const int q    = blockIdx.x & 3;  // column quarter 0..3
  const int b0   = g * 16;
  const int lc   = wlow * 16 + n16;         // local col 0..63
  const int c    = q * 64 + lc;             // own global h-col

  __shared__ __align__(16) bf16  Abuf[16][520];   // [x_t | h-then-rh]
  __shared__ __align__(16) float gbuf[16][36];
  __shared__ __align__(16) bf16  gact[16][40];
  __shared__ __align__(16) bf16  g2act[16][40];
  __shared__ float red[4][64][17];                // hi1 partials
  __shared__ float lngs[32], lnbs[32];
  // one-time staged weight slices (pitches coprime-with-8 granules: no hot spots)
  __shared__ __align__(16) bf16 P2L[64 * 264];    // 33.8 KB
  __shared__ __align__(16) bf16 P1L[32 * 264];    // 16.9 KB
  __shared__ __align__(16) bf16 g3L[3 * 64 * 40]; // 15.4 KB
  __shared__ __align__(16) bf16 g2L[1024];        //  2.0 KB

  if (tid < 32) { lngs[tid] = ln_g[tid]; lnbs[tid] = ln_b[tid]; }

  const int ep = *epoch_p;
  const float scale = fminf(1.0f, fmaxf(0.0f, ((float)ep - 5.0f) / 40.0f));

  const float brz_r = Wrz_b[c];
  const float brz_z = Wrz_b[256 + c];
  const float bwn   = Wn_b[c];
  const float bg3e  = g3_b[c];
  const float bg3t  = g3_b[256 + c];
  const float bg3a  = g3_b[512 + c];
  const float c2v   = c2f[c];
  const float c1v   = (wlow < 2) ? c1f[wlow * 16 + n16] : 0.0f;
  const float g2bv0 = g2_b[n16];
  const float g2bv1 = g2_b[16 + n16];

  const int k0 = hi * 4;              // this wave's K-quarter base

  // ---- one-time: big-GEMM B-fragments into registers (96 VGPR) ----
  bf16x8 Br[8], Bz[8], Bn[8];
  {
    const bf16* wrz = WrzT + (long)c * 512 + quad * 8;
    const bf16* wn  = WnT  + (long)c * 512 + quad * 8;
    #pragma unroll
    for (int i = 0; i < 4; ++i) {
      Br[i]     = *(const bf16x8*)(wrz + (k0 + i) * 32);
      Br[4 + i] = *(const bf16x8*)(wrz + (8 + k0 + i) * 32);
      Bz[i]     = *(const bf16x8*)(wrz + 256 * 512 + (k0 + i) * 32);
      Bz[4 + i] = *(const bf16x8*)(wrz + 256 * 512 + (8 + k0 + i) * 32);
      Bn[i]     = *(const bf16x8*)(wn + (k0 + i) * 32);
      Bn[4 + i] = *(const bf16x8*)(wn + (8 + k0 + i) * 32);
    }
  }
  // ---- one-time: small weights into LDS ----
  for (int i = tid; i < 2048; i += 512) {          // P2 slice: 64 cols x 256
    int col = i >> 5, ch = i & 31;
    *(bf16x8*)&P2L[col * 264 + ch * 8] = *(const bf16x8*)(P2T + (long)(q * 64 + col) * 256 + ch * 8);
  }
  for (int i = tid; i < 1024; i += 512) {          // P1: 32 cols x 256
    int col = i >> 5, ch = i & 31;
    *(bf16x8*)&P1L[col * 264 + ch * 8] = *(const bf16x8*)(P1T + (long)col * 256 + ch * 8);
  }
  for (int i = tid; i < 768; i += 512) {           // g3: 3 sets x 64 cols x 32
    int s = i >> 8, col = (i >> 2) & 63, ch = i & 3;
    *(bf16x8*)&g3L[(s * 64 + col) * 40 + ch * 8] = *(const bf16x8*)(g3T + (long)(s * 256 + q * 64 + col) * 32 + ch * 8);
  }
  for (int i = tid; i < 128; i += 512)             // g2: 32x32
    *(bf16x8*)&g2L[i * 8] = *(const bf16x8*)(g2T + i * 8);

  // own-column fp32 h state (hi0 lanes authoritative)
  float hreg[4];
  #pragma unroll
  for (int r = 0; r < 4; ++r)
    hreg[r] = h0[(long)(b0 + quad * 4 + r) * 256 + c];

  const int srow = tid >> 5;          // 0..15
  const int scol = (tid & 31) * 8;    // 0..248

  { // stage x_0 and full h0 (bf16) into Abuf (8 cols per thread)
    const float* hp = h0 + (long)(b0 + srow) * 256 + scol;
    const float* xp = out + ((long)(b0 + srow) * 256 + 0) * 256 + scol;
    bf16x8 xv, hv;
    #pragma unroll
    for (int j = 0; j < 8; ++j) { xv[j] = (bf16)xp[j]; hv[j] = (bf16)hp[j]; }
    *(bf16x8*)&Abuf[srow][scol]       = xv;
    *(bf16x8*)&Abuf[srow][256 + scol] = hv;
  }
  __syncthreads();

  const bf16* Ab = &Abuf[n16][quad * 8];
  u32* rhF = rhflag + g * 16;
  u32* hF  = hflag  + g * 16;

  for (int t = 0; t < 256; ++t) {
    const bool notlast = (t < 255);

    // prefetch x_{t+1} (8 f32/thread; staged at S2)
    f32x4 xr0 = {}, xr1 = {};
    if (notlast) {
      const float* xp = out + ((long)(b0 + srow) * 256 + (t + 1)) * 256 + scol;
      xr0 = *(const f32x4*)(xp);
      xr1 = *(const f32x4*)(xp + 4);
    }

    // ---- S1: x-part GEMMs (h-exchange RTT shadow) ----
    f32x4 accr = {}, accz = {}, accn = {}, accdh = {}, accg = {};
    #pragma unroll
    for (int ks = 0; ks < 4; ++ks) {
      bf16x8 a = *(const bf16x8*)(Ab + (k0 + ks) * 32);
      accr = mfma16(a, Br[ks], accr);
      accz = mfma16(a, Bz[ks], accz);
      accn = mfma16(a, Bn[ks], accn);
    }

    // ---- S2: h_t readback + x_{t+1} staging ----
    if (t > 0 && tid == 320) {
      const u32 tgt = 4u * (u32)t;
      while (__hip_atomic_load(hF, __ATOMIC_RELAXED, __HIP_MEMORY_SCOPE_AGENT) < tgt) {}
    }
    __syncthreads();                                               // bar A
    if (t > 0) {
      const u64* hp = (const u64*)(out + ((long)(b0 + srow) * 256 + (t - 1)) * 256 + scol);
      bf16x8 o;
      #pragma unroll
      for (int j = 0; j < 4; ++j) {
        u64 v = __hip_atomic_load(hp + j, __ATOMIC_RELAXED, __HIP_MEMORY_SCOPE_AGENT);
        o[2 * j]     = (bf16)__builtin_bit_cast(float, (u32)(v & 0xffffffffull));
        o[2 * j + 1] = (bf16)__builtin_bit_cast(float, (u32)(v >> 32));
      }
      *(bf16x8*)&Abuf[srow][256 + scol] = o;
    }
    if (notlast) {
      bf16x8 v;
      #pragma unroll
      for (int j = 0; j < 4; ++j) { v[j] = (bf16)xr0[j]; v[4 + j] = (bf16)xr1[j]; }
      *(bf16x8*)&Abuf[srow][scol] = v;
    }
    __syncthreads();                                               // bar B

    // ---- S3: h-part GEMMs ----
    #pragma unroll
    for (int ks = 0; ks < 4; ++ks) {
      bf16x8 a = *(const bf16x8*)(Ab + (8 + k0 + ks) * 32);
      accr = mfma16(a, Br[4 + ks], accr);
      accz = mfma16(a, Bz[4 + ks], accz);
    }
    #pragma unroll
    for (int ks = 0; ks < 4; ++ks) {
      const int kk = k0 + ks;
      bf16x8 a = *(const bf16x8*)(Ab + 256 + kk * 32);
      accdh = mfma16(a, *(const bf16x8*)&P2L[lc * 264 + kk * 32 + quad * 8], accdh);
      if (wlow < 2)
        accg = mfma16(a, *(const bf16x8*)&P1L[(wlow * 16 + n16) * 264 + kk * 32 + quad * 8], accg);
    }

    // ---- R1: pair-reduce accr, accg (hi1 -> LDS) ----
    if (hi) {
      #pragma unroll
      for (int r = 0; r < 4; ++r) red[wlow][lane][r] = accr[r];
      if (wlow < 2) {
        #pragma unroll
        for (int r = 0; r < 4; ++r) red[wlow][lane][4 + r] = accg[r];
      }
    }
    __syncthreads();                                               // bar C

    // ---- S4: r gate; publish rh; gbuf (hi0 only) ----
    if (!hi) {
      u64 pk = 0;
      #pragma unroll
      for (int r = 0; r < 4; ++r) {
        float rv = sigm(accr[r] + red[wlow][lane][r] + brz_r);
        pk |= (u64)bfbits(rv * hreg[r]) << (16 * r);
      }
      __hip_atomic_store(rhx + ((long)(g * 256 + c)) * 4 + quad, pk,
                         __ATOMIC_RELAXED, __HIP_MEMORY_SCOPE_AGENT);
      if (wlow < 2) {
        #pragma unroll
        for (int r = 0; r < 4; ++r)
          gbuf[quad * 4 + r][wlow * 16 + n16] = accg[r] + red[wlow][lane][4 + r] + c1v;
      }
    }
    asm volatile("s_waitcnt vmcnt(0)" ::: "memory");
    __syncthreads();                                               // bar D
    if (tid == 256)
      __hip_atomic_fetch_add(rhF, 1u, __ATOMIC_RELAXED, __HIP_MEMORY_SCOPE_AGENT);

    // ---- S5: LN + g2 (rh RTT shadow) ----
    if (tid < 16) {
      float mu = 0, s2 = 0;
      #pragma unroll
      for (int cc = 0; cc < 32; ++cc) { float v = gbuf[tid][cc]; mu += v; s2 += v * v; }
      mu *= (1.0f / 32.0f);
      s2 = s2 * (1.0f / 32.0f) - mu * mu;
      float rstd = rsqrtf(s2 + 1e-5f);
      #pragma unroll
      for (int cc = 0; cc < 32; ++cc) {
        float gn = (gbuf[tid][cc] - mu) * rstd * lngs[cc] + lnbs[cc];
        gact[tid][cc] = (bf16)fmaxf(gn, 0.0f);
      }
    }
    __syncthreads();                                               // bar E
    if (w == 0) {
      bf16x8 a = *(const bf16x8*)&gact[n16][quad * 8];
      f32x4 a0 = {}, a1 = {};
      a0 = mfma16(a, *(const bf16x8*)&g2L[n16 * 32 + quad * 8], a0);
      a1 = mfma16(a, *(const bf16x8*)&g2L[(16 + n16) * 32 + quad * 8], a1);
      #pragma unroll
      for (int r = 0; r < 4; ++r) {
        int row = quad * 4 + r;
        g2act[row][n16]      = (bf16)fmaxf(a0[r] + g2bv0, 0.0f);
        g2act[row][16 + n16] = (bf16)fmaxf(a1[r] + g2bv1, 0.0f);
      }
    }
    if (tid == 320) {
      const u32 tgt = 4u * (u32)(t + 1);
      while (__hip_atomic_load(rhF, __ATOMIC_RELAXED, __HIP_MEMORY_SCOPE_AGENT) < tgt) {}
    }
    __syncthreads();                                               // bar F

    // ---- S6: rh readback -> Abuf[:,256:512] (2 u64 per thread) ----
    {
      const int cc = tid >> 1;
      const int jb = (tid & 1) * 2;
      const u64* rp = rhx + ((long)(g * 256 + cc)) * 4 + jb;
      #pragma unroll
      for (int jj = 0; jj < 2; ++jj) {
        u64 v = __hip_atomic_load(rp + jj, __ATOMIC_RELAXED, __HIP_MEMORY_SCOPE_AGENT);
        #pragma unroll
        for (int r = 0; r < 4; ++r)
          *(u16*)&Abuf[(jb + jj) * 4 + r][256 + cc] = (u16)(v >> (16 * r));
      }
    }
    __syncthreads();                                               // bar G

    // ---- S7: accn rh-part; g3 (hi0) ----
    #pragma unroll
    for (int ks = 0; ks < 4; ++ks) {
      bf16x8 a = *(const bf16x8*)(Ab + (8 + k0 + ks) * 32);
      accn = mfma16(a, Bn[4 + ks], accn);
    }
    f32x4 acce = {}, acct = {}, acca = {};
    if (!hi) {
      bf16x8 a3 = *(const bf16x8*)&g2act[n16][quad * 8];
      acce = mfma16(a3, *(const bf16x8*)&g3L[(0 * 64 + lc) * 40 + quad * 8], acce);
      acct = mfma16(a3, *(const bf16x8*)&g3L[(1 * 64 + lc) * 40 + quad * 8], acct);
      acca = mfma16(a3, *(const bf16x8*)&g3L[(2 * 64 + lc) * 40 + quad * 8], acca);
    }
    // R2: pair-reduce accz, accdh, accn (hi1 -> LDS)
    if (hi) {
      #pragma unroll
      for (int r = 0; r < 4; ++r) {
        red[wlow][lane][r]     = accz[r];
        red[wlow][lane][4 + r] = accdh[r];
        red[wlow][lane][8 + r] = accn[r];
      }
    }
    __syncthreads();                                               // bar H

    // ---- S8: h update + publish (hi0) ----
    if (!hi) {
      float* op = out + ((long)(b0 + quad * 4) * 256 + t) * 256 + c;
      #pragma unroll
      for (int r = 0; r < 4; ++r) {
        float hv  = hreg[r];
        float zf  = sigm(accz[r] + red[wlow][lane][r] + brz_z);
        float dh  = accdh[r] + red[wlow][lane][4 + r] + c2v;
        float nn  = tanh_(accn[r] + red[wlow][lane][8 + r] + bwn);
        float eta = sigm(acce[r] + bg3e);
        float th  = fminf(softplus_(acct[r] + bg3t), 5.0f);
        float al  = sigm(acca[r] + bg3a) * scale;
        float s   = fminf(fmaxf(eta * hv - th * dh, -5.0f), 5.0f);
        float htl = (1.0f - al) * hv + al * s;
        float hn  = zf * htl + (1.0f - zf) * nn;
        hreg[r] = hn;
        __hip_atomic_store(op + (long)r * 65536, hn,
                           __ATOMIC_RELAXED, __HIP_MEMORY_SCOPE_AGENT);
      }
    }
    asm volatile("s_waitcnt vmcnt(0)" ::: "memory");
    __syncthreads();                                               // bar I
    if (tid == 256 && notlast)
      __hip_atomic_fetch_add(hF, 1u, __ATOMIC_RELAXED, __HIP_MEMORY_SCOPE_AGENT);
  }
}

// ---------------- launch ----------------

extern "C" void kernel_launch(void* const* d_in, const int* in_sizes, int n_in,
                              void* d_out, int out_size, void* d_ws, size_t ws_size,
                              hipStream_t stream) {
  const float* obs    = (const float*)d_in[0];
  const float* h0     = (const float*)d_in[1];
  const int*   epoch  = (const int*)  d_in[2];
  const float* obs_W  = (const float*)d_in[3];
  const float* obs_b  = (const float*)d_in[4];
  const float* enc_W  = (const float*)d_in[5];
  const float* enc_b  = (const float*)d_in[6];
  const float* pre_W  = (const float*)d_in[7];
  const float* pre_b  = (const float*)d_in[8];
  const float* pred_W = (const float*)d_in[9];
  const float* pred_b = (const float*)d_in[10];
  const float* Wrz_W  = (const float*)d_in[11];
  const float* Wrz_b  = (const float*)d_in[12];
  const float* Wn_W   = (const float*)d_in[13];
  const float* Wn_b   = (const float*)d_in[14];
  const float* g1_W   = (const float*)d_in[15];
  const float* g1_b   = (const float*)d_in[16];
  const float* ln_g   = (const float*)d_in[17];
  const float* ln_b   = (const float*)d_in[18];
  const float* g2_W   = (const float*)d_in[19];
  const float* g2_b   = (const float*)d_in[20];
  const float* g3_W   = (const float*)d_in[21];
  const float* g3_b   = (const float*)d_in[22];
  const float* dp_W   = (const float*)d_in[23];

  bf16* W = (bf16*)d_ws;
  bf16* WrzT  = W + 0;        // 262144 elems
  bf16* WnT   = W + 262144;   // 131072
  bf16* P2T   = W + 393216;   // 65536
  bf16* P1T   = W + 458752;   // 8192
  bf16* g2T   = W + 466944;   // 1024
  bf16* g3T   = W + 467968;   // 24576
  bf16* obsWT = W + 492544;   // 16384
  bf16* encWT = W + 508928;   // 65536
  bf16* preWT = W + 574464;   // 65536  -> weights end at byte 1280000
  float* c2f  = (float*)((char*)d_ws + 1280000);  // 256 f32
  float* c1f  = (float*)((char*)d_ws + 1281024);  // 32 f32
  u64*  rhx   = (u64*) ((char*)d_ws + 1281152);   // 64*256*4 u64 = 524288 B
  u32*  rhfl  = (u32*) ((char*)d_ws + 1805440);   // 64 groups * 16 u32 = 4096 B
  u32*  hfl   = (u32*) ((char*)d_ws + 1809536);   // 4096 B (contiguous after rhfl)
  float* out = (float*)d_out;

  k_zero<<<8, 256, 0, stream>>>(rhfl, 2048);      // zero both flag arrays

  k_transpose<<<1024, 256, 0, stream>>>(Wrz_W, WrzT, 512, 512);
  k_transpose<<<512,  256, 0, stream>>>(Wn_W,  WnT,  512, 256);
  k_transpose<<<4,    256, 0, stream>>>(g2_W,  g2T,  32,  32);
  k_transpose<<<96,   256, 0, stream>>>(g3_W,  g3T,  32,  768);
  k_transpose<<<64,   256, 0, stream>>>(obs_W, obsWT, 64, 256);
  k_transpose<<<256,  256, 0, stream>>>(enc_W, encWT, 256, 256);
  k_transpose<<<256,  256, 0, stream>>>(pre_W, preWT, 256, 256);
  k_p2<<<256, 256, 0, stream>>>(pred_W, dp_W, P2T);
  k_p1<<<32,  256, 0, stream>>>(pred_W, g1_W, P1T);
  k_cvec<<<1, 256, 0, stream>>>(pred_b, dp_W, g1_W, g1_b, c2f, c1f);

  k_phase1<<<4096, 256, 0, stream>>>(obs, obsWT, encWT, preWT, obs_b, enc_b, pre_b, out);
  k_phase2<<<256, 512, 0, stream>>>(h0, epoch, out, WrzT, WnT, P2T, P1T, g2T, g3T,
                                    c2f, c1f, Wrz_b, Wn_b, g2_b, g3_b, ln_g, ln_b,
                                    rhx, rhfl, hfl);

  (void)in_sizes; (void)n_in; (void)out_size; (void)ws_size;
}